// Round 4
// baseline (3246.372 us; speedup 1.0000x reference)
//
#include <hip/hip_runtime.h>
#include <cstdint>
#include <cstddef>

// ======== DIAGNOSTIC ROUND: every kernel body wrapped in REP=8 internal loop.
// Launch count/graph unchanged; all kernels are pure idempotent overwrites so
// outputs are identical. dur8 = 8*S + V  ->  S=(dur8-485)/7, V=485-S.
// Inflated instances (>325us) displace the ws-poison fills from rocprof top-5,
// giving per-kernel MfmaUtil/HBM/conflict counters for the first time.
#define REP 8

// ---------------- types / helpers ----------------
typedef __attribute__((ext_vector_type(4))) float f32x4;
typedef __attribute__((ext_vector_type(8))) unsigned short u16x8;
typedef __attribute__((ext_vector_type(4))) unsigned short u16x4;
typedef __bf16 bf16x8 __attribute__((ext_vector_type(8)));

__device__ __forceinline__ unsigned short f2bf(float f) {
  unsigned u = __builtin_bit_cast(unsigned, f);
  u += 0x7FFF + ((u >> 16) & 1);            // round-to-nearest-even
  return (unsigned short)(u >> 16);
}

__device__ __forceinline__ void mfma16x16x32(f32x4& acc, u16x8 a, u16x8 b) {
  acc = __builtin_amdgcn_mfma_f32_16x16x32_bf16(
      __builtin_bit_cast(bf16x8, a), __builtin_bit_cast(bf16x8, b), acc, 0, 0, 0);
}

typedef __attribute__((address_space(1))) const unsigned int as1_u32;
typedef __attribute__((address_space(3))) unsigned int as3_u32;
__device__ __forceinline__ void load_lds16(const void* g, void* l) {
  __builtin_amdgcn_global_load_lds((as1_u32*)g, (as3_u32*)l, 16, 0, 0);
}

// log2(e)/sqrt(128)
#define QSCALE2 0.12751745f

// ---------------- kernel 1: rope table ----------------
__global__ void k_sincos(float2* __restrict__ tab) {
  for (int rep = 0; rep < REP; ++rep) {
    int i = blockIdx.x * blockDim.x + threadIdx.x;
    if (i >= 2048 * 64) continue;
    int t = i >> 6, f = i & 63;
    float inv = expf(-(float)f * 0.14391156831212787f);
    float ang = (float)t * inv;
    tab[i] = make_float2(cosf(ang), sinf(ang));
  }
}

// ---------------- kernel 2: fused f32 -> bf16 converts ----------------
__global__ void k_cvt_all(const float* __restrict__ hs, const float* __restrict__ wq,
                          const float* __restrict__ wk, const float* __restrict__ wv,
                          const float* __restrict__ wo,
                          unsigned short* __restrict__ hs_bf, unsigned short* __restrict__ w_bf) {
  const int total = 10485760;
  int stride = gridDim.x * blockDim.x;
  for (int rep = 0; rep < REP; ++rep) {
    for (int i = blockIdx.x * blockDim.x + threadIdx.x; i < total; i += stride) {
      const float4* src;
      unsigned short* dst;
      long j;
      if (i < 1048576) { src = (const float4*)hs; j = i; dst = hs_bf + (size_t)i * 4; }
      else {
        int t = i - 1048576;
        dst = w_bf + (size_t)t * 4;
        if (t < 4194304)      { src = (const float4*)wq; j = t; }
        else if (t < 4718592) { src = (const float4*)wk; j = t - 4194304; }
        else if (t < 5242880) { src = (const float4*)wv; j = t - 4718592; }
        else                  { src = (const float4*)wo; j = t - 5242880; }
      }
      float4 v = src[j];
      u16x4 o = { f2bf(v.x), f2bf(v.y), f2bf(v.z), f2bf(v.w) };
      *(u16x4*)dst = o;
    }
  }
}

// ---------------- kernel 3: bf16 GEMM with split-K ----------------
__global__ __launch_bounds__(256) void k_gemm_bt(
    const unsigned short* __restrict__ A, const unsigned short* __restrict__ Bt,
    float* __restrict__ C, int M, int N, int K, int KC) {
  __shared__ unsigned short lA[2][128 * 32];
  __shared__ unsigned short lB[2][128 * 32];
  const int tid = threadIdx.x;
  const int w = tid >> 6, lane = tid & 63;
  const int wm = w >> 1, wn = w & 1;
  const int m0 = blockIdx.y * 128, n0 = blockIdx.x * 128;
  const int k0 = blockIdx.z * KC;
  const int lr = lane & 15, lg = lane >> 4;
  float* Cp = C + (size_t)blockIdx.z * M * N;

  const int srow = w * 32 + (lane >> 2);
  const int scol = (lane & 3) * 8;
  const unsigned short* gA = A + (size_t)(m0 + srow) * K + scol;
  const unsigned short* gB = Bt + (size_t)(n0 + srow) * K + scol;

  auto stage = [&](int buf, int kt) {
#pragma unroll
    for (int c = 0; c < 2; c++) {
      load_lds16(gA + (size_t)c * 16 * K + kt, &lA[buf][(w * 32 + c * 16) * 32]);
      load_lds16(gB + (size_t)c * 16 * K + kt, &lB[buf][(w * 32 + c * 16) * 32]);
    }
  };

  for (int rep = 0; rep < REP; ++rep) {
    f32x4 acc[4][4];
#pragma unroll
    for (int i = 0; i < 4; i++)
#pragma unroll
      for (int j = 0; j < 4; j++) acc[i][j] = (f32x4){0.f, 0.f, 0.f, 0.f};

    stage(0, k0);
    __syncthreads();
    int cur = 0;
    for (int kt = k0; kt < k0 + KC; kt += 32) {
      if (kt + 32 < k0 + KC) stage(cur ^ 1, kt + 32);
      u16x8 af[4], bf[4];
#pragma unroll
      for (int i = 0; i < 4; i++) af[i] = *(const u16x8*)&lA[cur][(wm * 64 + i * 16 + lr) * 32 + lg * 8];
#pragma unroll
      for (int j = 0; j < 4; j++) bf[j] = *(const u16x8*)&lB[cur][(wn * 64 + j * 16 + lr) * 32 + lg * 8];
#pragma unroll
      for (int i = 0; i < 4; i++)
#pragma unroll
        for (int j = 0; j < 4; j++) mfma16x16x32(acc[i][j], af[i], bf[j]);
      __syncthreads();
      cur ^= 1;
    }
#pragma unroll
    for (int i = 0; i < 4; i++)
#pragma unroll
      for (int j = 0; j < 4; j++)
#pragma unroll
        for (int r = 0; r < 4; r++) {
          int row = m0 + wm * 64 + i * 16 + lg * 4 + r;
          int col = n0 + wn * 64 + j * 16 + lr;
          Cp[(size_t)row * N + col] = acc[i][j][r];
        }
    __syncthreads();   // cross-rep: C-writes/LDS reads done before rep+1 restages
  }
}

// ---------------- kernel 4: split-K reduce (4 partials) ----------------
__global__ void k_reduce4(const float4* __restrict__ p, float4* __restrict__ out,
                          int n4, size_t stride4) {
  int stridet = gridDim.x * blockDim.x;
  for (int rep = 0; rep < REP; ++rep) {
    for (int i = blockIdx.x * blockDim.x + threadIdx.x; i < n4; i += stridet) {
      float4 a = p[i], b = p[i + stride4], c = p[i + 2 * stride4], d = p[i + 3 * stride4];
      out[i] = make_float4((a.x + b.x) + (c.x + d.x), (a.y + b.y) + (c.y + d.y),
                           (a.z + b.z) + (c.z + d.z), (a.w + b.w) + (c.w + d.w));
    }
  }
}

// ---------------- kernel 5: fused post-GEMM1 (K build | V build | Q rope) ----------
__global__ void k_post(const float* __restrict__ past, const float* __restrict__ qkv,
                       float* __restrict__ outk, float* __restrict__ outv,
                       unsigned short* __restrict__ kr, unsigned short* __restrict__ vt,
                       unsigned short* __restrict__ qr, const float2* __restrict__ tab) {
  for (int rep = 0; rep < REP; ++rep) {
    int idx = blockIdx.x * blockDim.x + threadIdx.x;
    if (idx < 524288) {
      int d0 = idx & 63;
      int t = (idx >> 6) & 2047;
      int h = idx >> 17;
      float v1, v2;
      if (t < 1024) {
        const float* p = past + ((size_t)h * 1024 + t) * 128;
        v1 = p[d0]; v2 = p[d0 + 64];
      } else {
        const float* p = qkv + (size_t)(t - 1024) * 5120 + 4096 + h * 128;
        v1 = p[d0]; v2 = p[d0 + 64];
      }
      float* o = outk + ((size_t)h * 2048 + t) * 128;
      o[d0] = v1; o[d0 + 64] = v2;
      float2 cs = tab[t * 64 + d0];
      unsigned short* ko = kr + ((size_t)h * 2048 + t) * 128;
      ko[d0]      = f2bf(v1 * cs.x - v2 * cs.y);
      ko[d0 + 64] = f2bf(v2 * cs.x + v1 * cs.y);
    } else if (idx < 1572864) {
      int i = idx - 524288;
      int d = i & 127;
      int t = (i >> 7) & 2047;
      int h = i >> 18;
      float val = (t < 1024) ? past[4 * 1024 * 128 + ((size_t)h * 1024 + t) * 128 + d]
                             : qkv[(size_t)(t - 1024) * 5120 + 4608 + h * 128 + d];
      outv[((size_t)h * 2048 + t) * 128 + d] = val;
      vt[((size_t)h * 128 + d) * 2048 + t] = f2bf(val);
    } else {
      int i = idx - 1572864;
      int d0 = i & 63;
      int q = (i >> 6) & 1023;
      int h = i >> 16;
      const float* p = qkv + (size_t)q * 5120 + h * 128;
      float v1 = p[d0], v2 = p[d0 + 64];
      float2 cs = tab[(1024 + q) * 64 + d0];
      unsigned short* o = qr + ((size_t)h * 1024 + q) * 128;
      o[d0]      = f2bf((v1 * cs.x - v2 * cs.y) * QSCALE2);
      o[d0 + 64] = f2bf((v2 * cs.x + v1 * cs.y) * QSCALE2);
    }
  }
}

// ---------------- kernel 6: flash attention, swapped-QK^T softmax ----------------
__global__ __launch_bounds__(64) void k_attn(
    const unsigned short* __restrict__ qr,
    const unsigned short* __restrict__ kr,
    const unsigned short* __restrict__ vt,
    unsigned short* __restrict__ ctxb) {
  __shared__ unsigned short plds[16 * 40];
  const int bid = blockIdx.x;
  const int h = bid >> 6;
  const int qt = bid & 63;
  const int q0 = qt * 16;
  const int kvh = h >> 3;
  const int l = threadIdx.x;
  const int lr = l & 15, lg = l >> 4;

  for (int rep = 0; rep < REP; ++rep) {
    u16x8 qf[4];
    {
      const unsigned short* qb = qr + ((size_t)(h * 1024 + q0 + lr)) * 128 + lg * 8;
#pragma unroll
      for (int ks = 0; ks < 4; ks++) qf[ks] = *(const u16x8*)(qb + ks * 32);
    }
    f32x4 acc[8];
#pragma unroll
    for (int i = 0; i < 8; i++) acc[i] = (f32x4){0.f, 0.f, 0.f, 0.f};
    float m_r = -1e30f, l_r = 0.f;

    const int limit = 1024 + q0 + lr;
    const int ntiles = (1024 + q0 + 15) / 32 + 1;
    const unsigned short* kh = kr + (size_t)kvh * 2048 * 128;
    const unsigned short* vh = vt + (size_t)kvh * 128 * 2048;

    for (int t = 0; t < ntiles; t++) {
      const int kb = t * 32;
      f32x4 s[2];
#pragma unroll
      for (int sub = 0; sub < 2; sub++) {
        f32x4 a = (f32x4){0.f, 0.f, 0.f, 0.f};
        const unsigned short* kp = kh + (size_t)(kb + sub * 16 + lr) * 128 + lg * 8;
#pragma unroll
        for (int ks = 0; ks < 4; ks++) {
          u16x8 kf = *(const u16x8*)(kp + ks * 32);
          mfma16x16x32(a, kf, qf[ks]);
        }
        s[sub] = a;
      }
      float v[8];
#pragma unroll
      for (int r = 0; r < 4; r++) { v[r] = s[0][r]; v[4 + r] = s[1][r]; }
      if (kb + 31 > 1024 + q0) {
        const int kbase = kb + lg * 4;
#pragma unroll
        for (int r = 0; r < 4; r++) {
          if (kbase + r > limit)      v[r]     = -1e30f;
          if (kbase + 16 + r > limit) v[4 + r] = -1e30f;
        }
      }
      float tmax = v[0];
#pragma unroll
      for (int j = 1; j < 8; j++) tmax = fmaxf(tmax, v[j]);
      tmax = fmaxf(tmax, __shfl_xor(tmax, 16));
      tmax = fmaxf(tmax, __shfl_xor(tmax, 32));
      if (!__all(tmax <= m_r + 11.5f)) {
        float mn = fmaxf(m_r, tmax);
        float corr = exp2f(m_r - mn);
        m_r = mn;
        l_r *= corr;
#pragma unroll
        for (int nt = 0; nt < 8; nt++)
#pragma unroll
          for (int r = 0; r < 4; r++) acc[nt][r] *= corr;
      }
      float p[8];
      float psum = 0.f;
#pragma unroll
      for (int j = 0; j < 8; j++) { p[j] = exp2f(v[j] - m_r); psum += p[j]; }
      psum += __shfl_xor(psum, 16);
      psum += __shfl_xor(psum, 32);
      l_r += psum;
      unsigned wds[4];
#pragma unroll
      for (int j = 0; j < 4; j++) {
        unsigned lo = __builtin_bit_cast(unsigned, p[2 * j]) + 0x8000u;
        unsigned hi = __builtin_bit_cast(unsigned, p[2 * j + 1]) + 0x8000u;
        wds[j] = (hi & 0xFFFF0000u) | (lo >> 16);
      }
      char* pb = (char*)plds + lr * 80 + lg * 8;
      *(uint2*)(pb)      = make_uint2(wds[0], wds[1]);
      *(uint2*)(pb + 32) = make_uint2(wds[2], wds[3]);
      __syncthreads();
      u16x8 pf = *(const u16x8*)&plds[lr * 40 + lg * 8];
#pragma unroll
      for (int nt = 0; nt < 8; nt++) {
        const unsigned short* vp = vh + (size_t)(nt * 16 + lr) * 2048 + kb + lg * 8;
        u16x8 vf = *(const u16x8*)vp;
        mfma16x16x32(acc[nt], vf, pf);
      }
      __syncthreads();
    }
    float inv = 1.0f / l_r;
    unsigned short* ob = ctxb + (size_t)(q0 + lr) * 4096 + h * 128 + lg * 4;
#pragma unroll
    for (int nt = 0; nt < 8; nt++) {
      u16x4 o = { f2bf(acc[nt][0] * inv), f2bf(acc[nt][1] * inv),
                  f2bf(acc[nt][2] * inv), f2bf(acc[nt][3] * inv) };
      *(u16x4*)(ob + nt * 16) = o;
    }
  }
}

// ---------------- launch ----------------
extern "C" void kernel_launch(void* const* d_in, const int* in_sizes, int n_in,
                              void* d_out, int out_size, void* d_ws, size_t ws_size,
                              hipStream_t stream) {
  (void)in_sizes; (void)n_in; (void)out_size; (void)ws_size;
  const float* hs   = (const float*)d_in[0];
  const float* past = (const float*)d_in[1];
  const float* Wq = (const float*)d_in[3];
  const float* Wk = (const float*)d_in[4];
  const float* Wv = (const float*)d_in[5];
  const float* Wo = (const float*)d_in[6];

  float* out_attn = (float*)d_out;                 // [1024][4096]
  float* out_pk = out_attn + 4194304;              // [4][2048][128]
  float* out_pv = out_pk + 1048576;                // [4][2048][128]

  const size_t MB = 1048576;
  char* ws = (char*)d_ws;
  unsigned short* hs_bf   = (unsigned short*)(ws);              // 8 MB
  unsigned short* wqkv_bf = (unsigned short*)(ws + 8 * MB);     // 40 MB
  unsigned short* wo_bf   = (unsigned short*)(ws + 48 * MB);    // 32 MB
  float*          qkv     = (float*)(ws + 80 * MB);             // 20 MB
  float2*         tab     = (float2*)(ws + 100 * MB);           // 1 MB
  unsigned short* kr      = (unsigned short*)(ws + 101 * MB);   // 2 MB
  unsigned short* vt      = (unsigned short*)(ws + 103 * MB);   // 2 MB
  unsigned short* qr      = (unsigned short*)(ws + 105 * MB);   // 8 MB
  unsigned short* ctxb    = (unsigned short*)(ws + 113 * MB);   // 8 MB
  float*          gp      = (float*)(ws + 128 * MB);            // 80 MB

  k_sincos<<<512, 256, 0, stream>>>(tab);
  k_cvt_all<<<2048, 256, 0, stream>>>(hs, Wq, Wk, Wv, Wo, hs_bf, wqkv_bf);

  dim3 g1(5120 / 128, 1024 / 128, 4);
  k_gemm_bt<<<g1, 256, 0, stream>>>(hs_bf, wqkv_bf, gp, 1024, 5120, 4096, 1024);
  k_reduce4<<<2048, 256, 0, stream>>>((const float4*)gp, (float4*)qkv, 1310720, 1310720);

  k_post<<<14336, 256, 0, stream>>>(past, qkv, out_pk, out_pv, kr, vt, qr, tab);

  k_attn<<<32 * 64, 64, 0, stream>>>(qr, kr, vt, ctxb);

  dim3 g2(4096 / 128, 1024 / 128, 4);
  k_gemm_bt<<<g2, 256, 0, stream>>>(ctxb, wo_bf, gp, 1024, 4096, 4096, 1024);
  k_reduce4<<<2048, 256, 0, stream>>>((const float4*)gp, (float4*)out_attn, 1048576, 1048576);
}

// Round 5
// 450.305 us; speedup vs baseline: 7.2093x; 7.2093x over previous
//
#include <hip/hip_runtime.h>
#include <cstdint>
#include <cstddef>

// ---------------- types / helpers ----------------
typedef __attribute__((ext_vector_type(4))) float f32x4;
typedef __attribute__((ext_vector_type(8))) unsigned short u16x8;
typedef __attribute__((ext_vector_type(4))) unsigned short u16x4;
typedef __bf16 bf16x8 __attribute__((ext_vector_type(8)));

__device__ __forceinline__ unsigned short f2bf(float f) {
  unsigned u = __builtin_bit_cast(unsigned, f);
  u += 0x7FFF + ((u >> 16) & 1);            // round-to-nearest-even
  return (unsigned short)(u >> 16);
}

__device__ __forceinline__ void mfma16x16x32(f32x4& acc, u16x8 a, u16x8 b) {
  acc = __builtin_amdgcn_mfma_f32_16x16x32_bf16(
      __builtin_bit_cast(bf16x8, a), __builtin_bit_cast(bf16x8, b), acc, 0, 0, 0);
}

typedef __attribute__((address_space(1))) const unsigned int as1_u32;
typedef __attribute__((address_space(3))) unsigned int as3_u32;
__device__ __forceinline__ void load_lds16(const void* g, void* l) {
  __builtin_amdgcn_global_load_lds((as1_u32*)g, (as3_u32*)l, 16, 0, 0);
}

// log2(e)/sqrt(128)
#define QSCALE2 0.12751745f

// ---------------- kernel 1: rope table ----------------
__global__ void k_sincos(float2* __restrict__ tab) {
  int i = blockIdx.x * blockDim.x + threadIdx.x;
  if (i >= 2048 * 64) return;
  int t = i >> 6, f = i & 63;
  float inv = expf(-(float)f * 0.14391156831212787f);
  float ang = (float)t * inv;
  tab[i] = make_float2(cosf(ang), sinf(ang));
}

// ---------------- kernel 2: fused f32 -> bf16 converts ----------------
__global__ void k_cvt_all(const float* __restrict__ hs, const float* __restrict__ wq,
                          const float* __restrict__ wk, const float* __restrict__ wv,
                          const float* __restrict__ wo,
                          unsigned short* __restrict__ hs_bf, unsigned short* __restrict__ w_bf) {
  const int total = 10485760;
  int stride = gridDim.x * blockDim.x;
  for (int i = blockIdx.x * blockDim.x + threadIdx.x; i < total; i += stride) {
    const float4* src;
    unsigned short* dst;
    long j;
    if (i < 1048576) { src = (const float4*)hs; j = i; dst = hs_bf + (size_t)i * 4; }
    else {
      int t = i - 1048576;
      dst = w_bf + (size_t)t * 4;
      if (t < 4194304)      { src = (const float4*)wq; j = t; }
      else if (t < 4718592) { src = (const float4*)wk; j = t - 4194304; }
      else if (t < 5242880) { src = (const float4*)wv; j = t - 4718592; }
      else                  { src = (const float4*)wo; j = t - 5242880; }
    }
    float4 v = src[j];
    u16x4 o = { f2bf(v.x), f2bf(v.y), f2bf(v.z), f2bf(v.w) };
    *(u16x4*)dst = o;
  }
}

// ---------------- kernel 3: bf16 GEMM with split-K ----------------
__global__ __launch_bounds__(256) void k_gemm_bt(
    const unsigned short* __restrict__ A, const unsigned short* __restrict__ Bt,
    float* __restrict__ C, int M, int N, int K, int KC) {
  __shared__ unsigned short lA[2][128 * 32];
  __shared__ unsigned short lB[2][128 * 32];
  const int tid = threadIdx.x;
  const int w = tid >> 6, lane = tid & 63;
  const int wm = w >> 1, wn = w & 1;
  const int m0 = blockIdx.y * 128, n0 = blockIdx.x * 128;
  const int k0 = blockIdx.z * KC;
  const int lr = lane & 15, lg = lane >> 4;
  float* Cp = C + (size_t)blockIdx.z * M * N;

  f32x4 acc[4][4];
#pragma unroll
  for (int i = 0; i < 4; i++)
#pragma unroll
    for (int j = 0; j < 4; j++) acc[i][j] = (f32x4){0.f, 0.f, 0.f, 0.f};

  const int srow = w * 32 + (lane >> 2);
  const int scol = (lane & 3) * 8;
  const unsigned short* gA = A + (size_t)(m0 + srow) * K + scol;
  const unsigned short* gB = Bt + (size_t)(n0 + srow) * K + scol;

  auto stage = [&](int buf, int kt) {
#pragma unroll
    for (int c = 0; c < 2; c++) {
      load_lds16(gA + (size_t)c * 16 * K + kt, &lA[buf][(w * 32 + c * 16) * 32]);
      load_lds16(gB + (size_t)c * 16 * K + kt, &lB[buf][(w * 32 + c * 16) * 32]);
    }
  };

  stage(0, k0);
  __syncthreads();
  int cur = 0;
  for (int kt = k0; kt < k0 + KC; kt += 32) {
    if (kt + 32 < k0 + KC) stage(cur ^ 1, kt + 32);
    u16x8 af[4], bf[4];
#pragma unroll
    for (int i = 0; i < 4; i++) af[i] = *(const u16x8*)&lA[cur][(wm * 64 + i * 16 + lr) * 32 + lg * 8];
#pragma unroll
    for (int j = 0; j < 4; j++) bf[j] = *(const u16x8*)&lB[cur][(wn * 64 + j * 16 + lr) * 32 + lg * 8];
#pragma unroll
    for (int i = 0; i < 4; i++)
#pragma unroll
      for (int j = 0; j < 4; j++) mfma16x16x32(acc[i][j], af[i], bf[j]);
    __syncthreads();
    cur ^= 1;
  }
#pragma unroll
  for (int i = 0; i < 4; i++)
#pragma unroll
    for (int j = 0; j < 4; j++)
#pragma unroll
      for (int r = 0; r < 4; r++) {
        int row = m0 + wm * 64 + i * 16 + lg * 4 + r;
        int col = n0 + wn * 64 + j * 16 + lr;
        Cp[(size_t)row * N + col] = acc[i][j][r];
      }
}

// ---------------- kernel 4: split-K reduce (4 partials) ----------------
__global__ void k_reduce4(const float4* __restrict__ p, float4* __restrict__ out,
                          int n4, size_t stride4) {
  int stridet = gridDim.x * blockDim.x;
  for (int i = blockIdx.x * blockDim.x + threadIdx.x; i < n4; i += stridet) {
    float4 a = p[i], b = p[i + stride4], c = p[i + 2 * stride4], d = p[i + 3 * stride4];
    out[i] = make_float4((a.x + b.x) + (c.x + d.x), (a.y + b.y) + (c.y + d.y),
                         (a.z + b.z) + (c.z + d.z), (a.w + b.w) + (c.w + d.w));
  }
}

// ---------------- kernel 5: fused post-GEMM1 (K build | V build | Q rope) ----------
__global__ void k_post(const float* __restrict__ past, const float* __restrict__ qkv,
                       float* __restrict__ outk, float* __restrict__ outv,
                       unsigned short* __restrict__ kr, unsigned short* __restrict__ vt,
                       unsigned short* __restrict__ qr, const float2* __restrict__ tab) {
  int idx = blockIdx.x * blockDim.x + threadIdx.x;
  if (idx < 524288) {
    int d0 = idx & 63;
    int t = (idx >> 6) & 2047;
    int h = idx >> 17;
    float v1, v2;
    if (t < 1024) {
      const float* p = past + ((size_t)h * 1024 + t) * 128;
      v1 = p[d0]; v2 = p[d0 + 64];
    } else {
      const float* p = qkv + (size_t)(t - 1024) * 5120 + 4096 + h * 128;
      v1 = p[d0]; v2 = p[d0 + 64];
    }
    float* o = outk + ((size_t)h * 2048 + t) * 128;
    o[d0] = v1; o[d0 + 64] = v2;
    float2 cs = tab[t * 64 + d0];
    unsigned short* ko = kr + ((size_t)h * 2048 + t) * 128;
    ko[d0]      = f2bf(v1 * cs.x - v2 * cs.y);
    ko[d0 + 64] = f2bf(v2 * cs.x + v1 * cs.y);
  } else if (idx < 1572864) {
    int i = idx - 524288;
    int d = i & 127;
    int t = (i >> 7) & 2047;
    int h = i >> 18;
    float val = (t < 1024) ? past[4 * 1024 * 128 + ((size_t)h * 1024 + t) * 128 + d]
                           : qkv[(size_t)(t - 1024) * 5120 + 4608 + h * 128 + d];
    outv[((size_t)h * 2048 + t) * 128 + d] = val;
    vt[((size_t)h * 128 + d) * 2048 + t] = f2bf(val);
  } else {
    int i = idx - 1572864;
    int d0 = i & 63;
    int q = (i >> 6) & 1023;
    int h = i >> 16;
    const float* p = qkv + (size_t)q * 5120 + h * 128;
    float v1 = p[d0], v2 = p[d0 + 64];
    float2 cs = tab[(1024 + q) * 64 + d0];
    unsigned short* o = qr + ((size_t)h * 1024 + q) * 128;
    o[d0]      = f2bf((v1 * cs.x - v2 * cs.y) * QSCALE2);
    o[d0 + 64] = f2bf((v2 * cs.x + v1 * cs.y) * QSCALE2);
  }
}

// ---------------- kernel 6: flash attention, KV-split x2 (flash-decoding) --------
// grid (2048, 2): blockIdx.y = chunk. chunk0 = keys [0,1024) non-causal;
// chunk1 = keys [1024, 1024+q0+16) causal. Unnormalized f32 partials + (m,l)
// per row; k_combine merges. Doubles resident waves (8->16/CU) to hide the
// per-wave serial load->MFMA->softmax chain. V loads issued before softmax
// so their L2 latency hides under the VALU chain (T14, reg-staged).
__global__ __launch_bounds__(64) void k_attn_split(
    const unsigned short* __restrict__ qr,  // [32][1024][128] (pre-scaled, log2)
    const unsigned short* __restrict__ kr,  // [4][2048][128]
    const unsigned short* __restrict__ vt,  // [4][128][2048]
    float* __restrict__ pacc,               // [2][32][1024][128]
    float* __restrict__ pml) {              // [2][32][1024][2]
  __shared__ unsigned short plds[16 * 40];
  const int chunk = blockIdx.y;
  const int bid = blockIdx.x;
  const int h = bid >> 6;
  const int qt = bid & 63;
  const int q0 = qt * 16;
  const int kvh = h >> 3;
  const int l = threadIdx.x;
  const int lr = l & 15, lg = l >> 4;

  u16x8 qf[4];
  {
    const unsigned short* qb = qr + ((size_t)(h * 1024 + q0 + lr)) * 128 + lg * 8;
#pragma unroll
    for (int ks = 0; ks < 4; ks++) qf[ks] = *(const u16x8*)(qb + ks * 32);
  }
  f32x4 acc[8];
#pragma unroll
  for (int i = 0; i < 8; i++) acc[i] = (f32x4){0.f, 0.f, 0.f, 0.f};
  float m_r = -1e30f, l_r = 0.f;

  const int limit = 1024 + q0 + lr;
  const int kb0 = chunk ? 1024 : 0;
  const int ntiles = chunk ? ((q0 + 47) >> 5) : 32;
  const unsigned short* kh = kr + (size_t)kvh * 2048 * 128;
  const unsigned short* vh = vt + (size_t)kvh * 128 * 2048;

  for (int t = 0; t < ntiles; t++) {
    const int kb = kb0 + t * 32;
    f32x4 s[2];
#pragma unroll
    for (int sub = 0; sub < 2; sub++) {
      f32x4 a = (f32x4){0.f, 0.f, 0.f, 0.f};
      const unsigned short* kp = kh + (size_t)(kb + sub * 16 + lr) * 128 + lg * 8;
#pragma unroll
      for (int ks = 0; ks < 4; ks++) {
        u16x8 kf = *(const u16x8*)(kp + ks * 32);
        mfma16x16x32(a, kf, qf[ks]);        // A=K, B=Q -> S^T
      }
      s[sub] = a;
    }
    // V prefetch: issue now, consume after softmax (latency hides under VALU)
    u16x8 vf[8];
#pragma unroll
    for (int nt = 0; nt < 8; nt++)
      vf[nt] = *(const u16x8*)(vh + (size_t)(nt * 16 + lr) * 2048 + kb + lg * 8);

    float v[8];
#pragma unroll
    for (int r = 0; r < 4; r++) { v[r] = s[0][r]; v[4 + r] = s[1][r]; }
    if (chunk && kb + 31 > 1024 + q0) {     // diagonal tiles only
      const int kbase = kb + lg * 4;
#pragma unroll
      for (int r = 0; r < 4; r++) {
        if (kbase + r > limit)      v[r]     = -1e30f;
        if (kbase + 16 + r > limit) v[4 + r] = -1e30f;
      }
    }
    float tmax = v[0];
#pragma unroll
    for (int j = 1; j < 8; j++) tmax = fmaxf(tmax, v[j]);
    tmax = fmaxf(tmax, __shfl_xor(tmax, 16));
    tmax = fmaxf(tmax, __shfl_xor(tmax, 32));
    if (!__all(tmax <= m_r + 11.5f)) {      // defer-max (T13)
      float mn = fmaxf(m_r, tmax);
      float corr = exp2f(m_r - mn);
      m_r = mn;
      l_r *= corr;
#pragma unroll
      for (int nt = 0; nt < 8; nt++)
#pragma unroll
        for (int r = 0; r < 4; r++) acc[nt][r] *= corr;
    }
    float p[8];
    float psum = 0.f;
#pragma unroll
    for (int j = 0; j < 8; j++) { p[j] = exp2f(v[j] - m_r); psum += p[j]; }
    psum += __shfl_xor(psum, 16);
    psum += __shfl_xor(psum, 32);
    l_r += psum;
    unsigned wds[4];
#pragma unroll
    for (int j = 0; j < 4; j++) {
      unsigned lo = __builtin_bit_cast(unsigned, p[2 * j]) + 0x8000u;
      unsigned hi = __builtin_bit_cast(unsigned, p[2 * j + 1]) + 0x8000u;
      wds[j] = (hi & 0xFFFF0000u) | (lo >> 16);
    }
    char* pb = (char*)plds + lr * 80 + lg * 8;
    *(uint2*)(pb)      = make_uint2(wds[0], wds[1]);
    *(uint2*)(pb + 32) = make_uint2(wds[2], wds[3]);
    __syncthreads();
    u16x8 pf = *(const u16x8*)&plds[lr * 40 + lg * 8];
#pragma unroll
    for (int nt = 0; nt < 8; nt++) mfma16x16x32(acc[nt], vf[nt], pf);  // A=V^T,B=P
    __syncthreads();
  }
  // store unnormalized partials; acc[nt][r] = ctx[q0+lr][nt*16+lg*4+r]
  const size_t row = (size_t)(chunk * 32 + h) * 1024 + q0 + lr;
  float* pa = pacc + row * 128 + lg * 4;
#pragma unroll
  for (int nt = 0; nt < 8; nt++) *(f32x4*)(pa + nt * 16) = acc[nt];
  if (lg == 0) *(float2*)(pml + row * 2) = make_float2(m_r, l_r);
}

// ---------------- kernel 7: combine KV-split partials -> ctx bf16 ----------------
__global__ void k_combine(const float* __restrict__ pacc, const float* __restrict__ pml,
                          unsigned short* __restrict__ ctxb) {
  int idx = blockIdx.x * blockDim.x + threadIdx.x;  // [32][1024][32 d4]
  if (idx >= 1048576) return;
  int d4 = idx & 31;
  int q = (idx >> 5) & 1023;
  int h = idx >> 15;
  size_t r0 = (size_t)h * 1024 + q;
  float2 ml0 = *(const float2*)(pml + r0 * 2);
  float2 ml1 = *(const float2*)(pml + (65536 + r0) * 2);
  float M = fmaxf(ml0.x, ml1.x);
  float w0 = exp2f(ml0.x - M), w1 = exp2f(ml1.x - M);
  float inv = 1.0f / (ml0.y * w0 + ml1.y * w1);
  f32x4 a0 = *(const f32x4*)(pacc + r0 * 128 + d4 * 4);
  f32x4 a1 = *(const f32x4*)(pacc + (size_t)4194304 + r0 * 128 + d4 * 4);
  u16x4 o;
#pragma unroll
  for (int j = 0; j < 4; j++) o[j] = f2bf((a0[j] * w0 + a1[j] * w1) * inv);
  *(u16x4*)(ctxb + (size_t)q * 4096 + h * 128 + d4 * 4) = o;
}

// ---------------- launch ----------------
extern "C" void kernel_launch(void* const* d_in, const int* in_sizes, int n_in,
                              void* d_out, int out_size, void* d_ws, size_t ws_size,
                              hipStream_t stream) {
  (void)in_sizes; (void)n_in; (void)out_size; (void)ws_size;
  const float* hs   = (const float*)d_in[0];
  const float* past = (const float*)d_in[1];
  const float* Wq = (const float*)d_in[3];
  const float* Wk = (const float*)d_in[4];
  const float* Wv = (const float*)d_in[5];
  const float* Wo = (const float*)d_in[6];

  float* out_attn = (float*)d_out;                 // [1024][4096]
  float* out_pk = out_attn + 4194304;              // [4][2048][128]
  float* out_pv = out_pk + 1048576;                // [4][2048][128]

  const size_t MB = 1048576;
  char* ws = (char*)d_ws;
  unsigned short* hs_bf   = (unsigned short*)(ws);              // 8 MB
  unsigned short* wqkv_bf = (unsigned short*)(ws + 8 * MB);     // 40 MB
  unsigned short* wo_bf   = (unsigned short*)(ws + 48 * MB);    // 32 MB
  float*          qkv     = (float*)(ws + 80 * MB);             // 20 MB
  float2*         tab     = (float2*)(ws + 100 * MB);           // 1 MB
  unsigned short* kr      = (unsigned short*)(ws + 101 * MB);   // 2 MB
  unsigned short* vt      = (unsigned short*)(ws + 103 * MB);   // 2 MB
  unsigned short* qr      = (unsigned short*)(ws + 105 * MB);   // 8 MB
  unsigned short* ctxb    = (unsigned short*)(ws + 113 * MB);   // 8 MB
  float*          gp      = (float*)(ws + 128 * MB);            // 80 MB GEMM partials
  float*          pacc    = (float*)(ws + 208 * MB);            // 34 MB attn partials
  float*          pml     = (float*)(ws + 244 * MB);            // 0.5 MB (m,l)

  k_sincos<<<512, 256, 0, stream>>>(tab);
  k_cvt_all<<<2048, 256, 0, stream>>>(hs, Wq, Wk, Wv, Wo, hs_bf, wqkv_bf);

  dim3 g1(5120 / 128, 1024 / 128, 4);
  k_gemm_bt<<<g1, 256, 0, stream>>>(hs_bf, wqkv_bf, gp, 1024, 5120, 4096, 1024);
  k_reduce4<<<2048, 256, 0, stream>>>((const float4*)gp, (float4*)qkv, 1310720, 1310720);

  k_post<<<14336, 256, 0, stream>>>(past, qkv, out_pk, out_pv, kr, vt, qr, tab);

  dim3 ga(2048, 2);
  k_attn_split<<<ga, 64, 0, stream>>>(qr, kr, vt, pacc, pml);
  k_combine<<<4096, 256, 0, stream>>>(pacc, pml, ctxb);

  dim3 g2(4096 / 128, 1024 / 128, 4);
  k_gemm_bt<<<g2, 256, 0, stream>>>(ctxb, wo_bf, gp, 1024, 4096, 4096, 1024);
  k_reduce4<<<2048, 256, 0, stream>>>((const float4*)gp, (float4*)out_attn, 1048576, 1048576);
}

// Round 6
// 422.764 us; speedup vs baseline: 7.6789x; 1.0651x over previous
//
#include <hip/hip_runtime.h>
#include <cstdint>
#include <cstddef>

// ---------------- types / helpers ----------------
typedef __attribute__((ext_vector_type(4))) float f32x4;
typedef __attribute__((ext_vector_type(8))) unsigned short u16x8;
typedef __attribute__((ext_vector_type(4))) unsigned short u16x4;
typedef __bf16 bf16x8 __attribute__((ext_vector_type(8)));

__device__ __forceinline__ unsigned short f2bf(float f) {
  unsigned u = __builtin_bit_cast(unsigned, f);
  u += 0x7FFF + ((u >> 16) & 1);            // round-to-nearest-even
  return (unsigned short)(u >> 16);
}

__device__ __forceinline__ void mfma16x16x32(f32x4& acc, u16x8 a, u16x8 b) {
  acc = __builtin_amdgcn_mfma_f32_16x16x32_bf16(
      __builtin_bit_cast(bf16x8, a), __builtin_bit_cast(bf16x8, b), acc, 0, 0, 0);
}

typedef __attribute__((address_space(1))) const unsigned int as1_u32;
typedef __attribute__((address_space(3))) unsigned int as3_u32;
__device__ __forceinline__ void load_lds16(const void* g, void* l) {
  __builtin_amdgcn_global_load_lds((as1_u32*)g, (as3_u32*)l, 16, 0, 0);
}

// log2(e)/sqrt(128)
#define QSCALE2 0.12751745f

// ---------------- kernel 1: fused converts + rope table (1 launch) ----------------
// f4 ranges: hs [0,1048576) | w [1048576,10485760) | sincos tail [10485760,10616832)
__global__ void k_cvt_all(const float* __restrict__ hs, const float* __restrict__ wq,
                          const float* __restrict__ wk, const float* __restrict__ wv,
                          const float* __restrict__ wo,
                          unsigned short* __restrict__ hs_bf, unsigned short* __restrict__ w_bf,
                          float2* __restrict__ tab) {
  const int total = 10616832;
  int stride = gridDim.x * blockDim.x;
  for (int i = blockIdx.x * blockDim.x + threadIdx.x; i < total; i += stride) {
    if (i >= 10485760) {                    // sincos table, 2048x64
      int j = i - 10485760;
      int t = j >> 6, f = j & 63;
      float inv = expf(-(float)f * 0.14391156831212787f);  // 10000^(-f/64)
      float ang = (float)t * inv;
      tab[j] = make_float2(cosf(ang), sinf(ang));
      continue;
    }
    const float4* src;
    unsigned short* dst;
    long j;
    if (i < 1048576) { src = (const float4*)hs; j = i; dst = hs_bf + (size_t)i * 4; }
    else {
      int t = i - 1048576;
      dst = w_bf + (size_t)t * 4;           // q|k|v|o packed contiguously
      if (t < 4194304)      { src = (const float4*)wq; j = t; }
      else if (t < 4718592) { src = (const float4*)wk; j = t - 4194304; }
      else if (t < 5242880) { src = (const float4*)wv; j = t - 4718592; }
      else                  { src = (const float4*)wo; j = t - 5242880; }
    }
    float4 v = src[j];
    u16x4 o = { f2bf(v.x), f2bf(v.y), f2bf(v.z), f2bf(v.w) };
    *(u16x4*)dst = o;
  }
}

// ---------------- kernel 2: bf16 GEMM with split-K ----------------
__global__ __launch_bounds__(256) void k_gemm_bt(
    const unsigned short* __restrict__ A, const unsigned short* __restrict__ Bt,
    float* __restrict__ C, int M, int N, int K, int KC) {
  __shared__ unsigned short lA[2][128 * 32];
  __shared__ unsigned short lB[2][128 * 32];
  const int tid = threadIdx.x;
  const int w = tid >> 6, lane = tid & 63;
  const int wm = w >> 1, wn = w & 1;
  const int m0 = blockIdx.y * 128, n0 = blockIdx.x * 128;
  const int k0 = blockIdx.z * KC;
  const int lr = lane & 15, lg = lane >> 4;
  float* Cp = C + (size_t)blockIdx.z * M * N;

  f32x4 acc[4][4];
#pragma unroll
  for (int i = 0; i < 4; i++)
#pragma unroll
    for (int j = 0; j < 4; j++) acc[i][j] = (f32x4){0.f, 0.f, 0.f, 0.f};

  const int srow = w * 32 + (lane >> 2);
  const int scol = (lane & 3) * 8;
  const unsigned short* gA = A + (size_t)(m0 + srow) * K + scol;
  const unsigned short* gB = Bt + (size_t)(n0 + srow) * K + scol;

  auto stage = [&](int buf, int kt) {
#pragma unroll
    for (int c = 0; c < 2; c++) {
      load_lds16(gA + (size_t)c * 16 * K + kt, &lA[buf][(w * 32 + c * 16) * 32]);
      load_lds16(gB + (size_t)c * 16 * K + kt, &lB[buf][(w * 32 + c * 16) * 32]);
    }
  };

  stage(0, k0);
  __syncthreads();
  int cur = 0;
  for (int kt = k0; kt < k0 + KC; kt += 32) {
    if (kt + 32 < k0 + KC) stage(cur ^ 1, kt + 32);
    u16x8 af[4], bf[4];
#pragma unroll
    for (int i = 0; i < 4; i++) af[i] = *(const u16x8*)&lA[cur][(wm * 64 + i * 16 + lr) * 32 + lg * 8];
#pragma unroll
    for (int j = 0; j < 4; j++) bf[j] = *(const u16x8*)&lB[cur][(wn * 64 + j * 16 + lr) * 32 + lg * 8];
#pragma unroll
    for (int i = 0; i < 4; i++)
#pragma unroll
      for (int j = 0; j < 4; j++) mfma16x16x32(acc[i][j], af[i], bf[j]);
    __syncthreads();
    cur ^= 1;
  }
#pragma unroll
  for (int i = 0; i < 4; i++)
#pragma unroll
    for (int j = 0; j < 4; j++)
#pragma unroll
      for (int r = 0; r < 4; r++) {
        int row = m0 + wm * 64 + i * 16 + lg * 4 + r;
        int col = n0 + wn * 64 + j * 16 + lr;
        Cp[(size_t)row * N + col] = acc[i][j][r];
      }
}

// ---------------- kernel 3: split-K reduce (4 partials) — O-proj only ----------
__global__ void k_reduce4(const float4* __restrict__ p, float4* __restrict__ out,
                          int n4, size_t stride4) {
  int stridet = gridDim.x * blockDim.x;
  for (int i = blockIdx.x * blockDim.x + threadIdx.x; i < n4; i += stridet) {
    float4 a = p[i], b = p[i + stride4], c = p[i + 2 * stride4], d = p[i + 3 * stride4];
    out[i] = make_float4((a.x + b.x) + (c.x + d.x), (a.y + b.y) + (c.y + d.y),
                         (a.z + b.z) + (c.z + d.z), (a.w + b.w) + (c.w + d.w));
  }
}

// ---------------- kernel 4: fused post (reads GEMM1 partials directly) ----------
// gp: 4 x [1024][5120] fp32 partials; qkv(i) = sum of 4.
#define GP_S 5242880
__device__ __forceinline__ float gsum(const float* __restrict__ gp, size_t i) {
  return (gp[i] + gp[i + GP_S]) + (gp[i + 2 * (size_t)GP_S] + gp[i + 3 * (size_t)GP_S]);
}

__global__ void k_post(const float* __restrict__ past, const float* __restrict__ gp,
                       float* __restrict__ outk, float* __restrict__ outv,
                       unsigned short* __restrict__ kr, unsigned short* __restrict__ vt,
                       unsigned short* __restrict__ qr, const float2* __restrict__ tab) {
  int idx = blockIdx.x * blockDim.x + threadIdx.x;
  if (idx < 524288) {
    // K: new_past (pre-RoPE) + RoPE'd bf16 cache
    int d0 = idx & 63;
    int t = (idx >> 6) & 2047;
    int h = idx >> 17;
    float v1, v2;
    if (t < 1024) {
      const float* p = past + ((size_t)h * 1024 + t) * 128;
      v1 = p[d0]; v2 = p[d0 + 64];
    } else {
      size_t base = (size_t)(t - 1024) * 5120 + 4096 + h * 128;
      v1 = gsum(gp, base + d0); v2 = gsum(gp, base + d0 + 64);
    }
    float* o = outk + ((size_t)h * 2048 + t) * 128;
    o[d0] = v1; o[d0 + 64] = v2;
    float2 cs = tab[t * 64 + d0];
    unsigned short* ko = kr + ((size_t)h * 2048 + t) * 128;
    ko[d0]      = f2bf(v1 * cs.x - v2 * cs.y);
    ko[d0 + 64] = f2bf(v2 * cs.x + v1 * cs.y);
  } else if (idx < 1572864) {
    // V: new_past + transposed bf16 cache [4][128][2048]
    int i = idx - 524288;
    int d = i & 127;
    int t = (i >> 7) & 2047;
    int h = i >> 18;
    float val = (t < 1024) ? past[4 * 1024 * 128 + ((size_t)h * 1024 + t) * 128 + d]
                           : gsum(gp, (size_t)(t - 1024) * 5120 + 4608 + h * 128 + d);
    outv[((size_t)h * 2048 + t) * 128 + d] = val;
    vt[((size_t)h * 128 + d) * 2048 + t] = f2bf(val);
  } else {
    // Q: RoPE, pre-scaled by log2(e)/sqrt(D)
    int i = idx - 1572864;
    int d0 = i & 63;
    int q = (i >> 6) & 1023;
    int h = i >> 16;
    size_t base = (size_t)q * 5120 + h * 128;
    float v1 = gsum(gp, base + d0), v2 = gsum(gp, base + d0 + 64);
    float2 cs = tab[(1024 + q) * 64 + d0];
    unsigned short* o = qr + ((size_t)h * 1024 + q) * 128;
    o[d0]      = f2bf((v1 * cs.x - v2 * cs.y) * QSCALE2);
    o[d0 + 64] = f2bf((v2 * cs.x + v1 * cs.y) * QSCALE2);
  }
}

// ---------------- kernel 5: flash attention, 4-wave in-block KV-split ----------
// grid 2048 (h*64+qt), 256 threads. Wave w handles tiles t = w, w+4, ... of
// T = 32+((q0+47)>>5) total; waves run barrier-free (per-wave plds slice, P
// write->read ordered by s_waitcnt lgkmcnt(0)). Epilogue: pairwise LDS combine
// (m,l,acc) with padded slabs; barriers only there (uniform). No global
// partials, no combine kernel.
__global__ __launch_bounds__(256) void k_attn4(
    const unsigned short* __restrict__ qr,  // [32][1024][128] (pre-scaled, log2)
    const unsigned short* __restrict__ kr,  // [4][2048][128] (RoPE'd)
    const unsigned short* __restrict__ vt,  // [4][128][2048]
    unsigned short* __restrict__ ctxb) {    // [1024][4096] bf16
  __shared__ unsigned short plds[4][16 * 40];   // per-wave P tile, 80B rows
  __shared__ float slabA[16][132];              // +4 pad: bank-spread epilogue
  __shared__ float slabB[16][132];
  __shared__ float mlds[4][16][2];
  const int bid = blockIdx.x;
  const int h = bid >> 6;
  const int qt = bid & 63;
  const int q0 = qt * 16;
  const int kvh = h >> 3;
  const int tid = threadIdx.x;
  const int w = tid >> 6, l = tid & 63;
  const int lr = l & 15, lg = l >> 4;

  u16x8 qf[4];
  {
    const unsigned short* qb = qr + ((size_t)(h * 1024 + q0 + lr)) * 128 + lg * 8;
#pragma unroll
    for (int ks = 0; ks < 4; ks++) qf[ks] = *(const u16x8*)(qb + ks * 32);
  }
  f32x4 acc[8];
#pragma unroll
  for (int i = 0; i < 8; i++) acc[i] = (f32x4){0.f, 0.f, 0.f, 0.f};
  float m_r = -1e30f, l_r = 0.f;

  const int limit = 1024 + q0 + lr;
  const int T = 32 + ((q0 + 47) >> 5);      // total 32-key tiles (33..64)
  const unsigned short* kh = kr + (size_t)kvh * 2048 * 128;
  const unsigned short* vh = vt + (size_t)kvh * 128 * 2048;

  for (int t = w; t < T; t += 4) {
    const int kb = t * 32;
    f32x4 s[2];
#pragma unroll
    for (int sub = 0; sub < 2; sub++) {
      f32x4 a = (f32x4){0.f, 0.f, 0.f, 0.f};
      const unsigned short* kp = kh + (size_t)(kb + sub * 16 + lr) * 128 + lg * 8;
#pragma unroll
      for (int ks = 0; ks < 4; ks++) {
        u16x8 kf = *(const u16x8*)(kp + ks * 32);
        mfma16x16x32(a, kf, qf[ks]);        // A=K, B=Q -> S^T
      }
      s[sub] = a;
    }
    // V loads issued early; latency hides under softmax VALU chain
    u16x8 vf[8];
#pragma unroll
    for (int nt = 0; nt < 8; nt++)
      vf[nt] = *(const u16x8*)(vh + (size_t)(nt * 16 + lr) * 2048 + kb + lg * 8);

    float v[8];
#pragma unroll
    for (int r = 0; r < 4; r++) { v[r] = s[0][r]; v[4 + r] = s[1][r]; }
    if (kb + 31 > 1024 + q0) {              // diagonal tiles only
      const int kbase = kb + lg * 4;
#pragma unroll
      for (int r = 0; r < 4; r++) {
        if (kbase + r > limit)      v[r]     = -1e30f;
        if (kbase + 16 + r > limit) v[4 + r] = -1e30f;
      }
    }
    float tmax = v[0];
#pragma unroll
    for (int j = 1; j < 8; j++) tmax = fmaxf(tmax, v[j]);
    tmax = fmaxf(tmax, __shfl_xor(tmax, 16));
    tmax = fmaxf(tmax, __shfl_xor(tmax, 32));
    if (!__all(tmax <= m_r + 11.5f)) {      // defer-max (T13)
      float mn = fmaxf(m_r, tmax);
      float corr = exp2f(m_r - mn);
      m_r = mn;
      l_r *= corr;
#pragma unroll
      for (int nt = 0; nt < 8; nt++)
#pragma unroll
        for (int r = 0; r < 4; r++) acc[nt][r] *= corr;
    }
    float p[8];
    float psum = 0.f;
#pragma unroll
    for (int j = 0; j < 8; j++) { p[j] = exp2f(v[j] - m_r); psum += p[j]; }
    psum += __shfl_xor(psum, 16);
    psum += __shfl_xor(psum, 32);
    l_r += psum;
    unsigned wds[4];
#pragma unroll
    for (int j = 0; j < 4; j++) {
      unsigned lo = __builtin_bit_cast(unsigned, p[2 * j]) + 0x8000u;
      unsigned hi = __builtin_bit_cast(unsigned, p[2 * j + 1]) + 0x8000u;
      wds[j] = (hi & 0xFFFF0000u) | (lo >> 16);
    }
    char* pb = (char*)&plds[w][0] + lr * 80 + lg * 8;
    *(uint2*)(pb)      = make_uint2(wds[0], wds[1]);
    *(uint2*)(pb + 32) = make_uint2(wds[2], wds[3]);
    asm volatile("s_waitcnt lgkmcnt(0)" ::: "memory");   // P write -> read (1 wave)
    u16x8 pf = *(const u16x8*)&plds[w][lr * 40 + lg * 8];
#pragma unroll
    for (int nt = 0; nt < 8; nt++) mfma16x16x32(acc[nt], vf[nt], pf);  // A=V^T,B=P
  }

  // ---- epilogue: combine 4 waves' (m,l,acc) via LDS ----
  if (lg == 0) { mlds[w][lr][0] = m_r; mlds[w][lr][1] = l_r; }
  __syncthreads();
  float M = fmaxf(fmaxf(mlds[0][lr][0], mlds[1][lr][0]),
                  fmaxf(mlds[2][lr][0], mlds[3][lr][0]));
  float L = 0.f;
#pragma unroll
  for (int i = 0; i < 4; i++) L += mlds[i][lr][1] * exp2f(mlds[i][lr][0] - M);
  float wt = exp2f(m_r - M);
#pragma unroll
  for (int nt = 0; nt < 8; nt++)
#pragma unroll
    for (int r = 0; r < 4; r++) acc[nt][r] *= wt;

  if (w == 1 || w == 3) {
    float* slab = (w == 1) ? &slabA[0][0] : &slabB[0][0];
#pragma unroll
    for (int nt = 0; nt < 8; nt++)
      *(f32x4*)&slab[lr * 132 + nt * 16 + lg * 4] = acc[nt];
  }
  __syncthreads();
  if (w == 0 || w == 2) {
    const float* slab = (w == 0) ? &slabA[0][0] : &slabB[0][0];
#pragma unroll
    for (int nt = 0; nt < 8; nt++) {
      f32x4 o = *(const f32x4*)&slab[lr * 132 + nt * 16 + lg * 4];
#pragma unroll
      for (int r = 0; r < 4; r++) acc[nt][r] += o[r];
    }
  }
  __syncthreads();
  if (w == 2) {
#pragma unroll
    for (int nt = 0; nt < 8; nt++)
      *(f32x4*)&slabA[0][lr * 132 + nt * 16 + lg * 4] = acc[nt];
  }
  __syncthreads();
  if (w == 0) {
    float inv = 1.0f / L;
    unsigned short* ob = ctxb + (size_t)(q0 + lr) * 4096 + h * 128 + lg * 4;
#pragma unroll
    for (int nt = 0; nt < 8; nt++) {
      f32x4 o = *(const f32x4*)&slabA[0][lr * 132 + nt * 16 + lg * 4];
      u16x4 ov = { f2bf((acc[nt][0] + o[0]) * inv), f2bf((acc[nt][1] + o[1]) * inv),
                   f2bf((acc[nt][2] + o[2]) * inv), f2bf((acc[nt][3] + o[3]) * inv) };
      *(u16x4*)(ob + nt * 16) = ov;
    }
  }
}

// ---------------- launch ----------------
extern "C" void kernel_launch(void* const* d_in, const int* in_sizes, int n_in,
                              void* d_out, int out_size, void* d_ws, size_t ws_size,
                              hipStream_t stream) {
  (void)in_sizes; (void)n_in; (void)out_size; (void)ws_size;
  const float* hs   = (const float*)d_in[0];
  const float* past = (const float*)d_in[1];
  // d_in[2] attention_mask: pure causal, synthesized analytically
  const float* Wq = (const float*)d_in[3];
  const float* Wk = (const float*)d_in[4];
  const float* Wv = (const float*)d_in[5];
  const float* Wo = (const float*)d_in[6];

  float* out_attn = (float*)d_out;                 // [1024][4096]
  float* out_pk = out_attn + 4194304;              // [4][2048][128]
  float* out_pv = out_pk + 1048576;                // [4][2048][128]

  const size_t MB = 1048576;
  char* ws = (char*)d_ws;
  unsigned short* hs_bf   = (unsigned short*)(ws);              // 8 MB
  unsigned short* wqkv_bf = (unsigned short*)(ws + 8 * MB);     // 40 MB [5120][4096]
  unsigned short* wo_bf   = (unsigned short*)(ws + 48 * MB);    // 32 MB [4096][4096]
  float2*         tab     = (float2*)(ws + 100 * MB);           // 1 MB
  unsigned short* kr      = (unsigned short*)(ws + 101 * MB);   // 2 MB
  unsigned short* vt      = (unsigned short*)(ws + 103 * MB);   // 2 MB
  unsigned short* qr      = (unsigned short*)(ws + 105 * MB);   // 8 MB
  unsigned short* ctxb    = (unsigned short*)(ws + 113 * MB);   // 8 MB
  float*          gp      = (float*)(ws + 128 * MB);            // 80 MB GEMM partials

  k_cvt_all<<<2048, 256, 0, stream>>>(hs, Wq, Wk, Wv, Wo, hs_bf, wqkv_bf, tab);

  dim3 g1(5120 / 128, 1024 / 128, 4);              // split-K=4: 1280 blocks
  k_gemm_bt<<<g1, 256, 0, stream>>>(hs_bf, wqkv_bf, gp, 1024, 5120, 4096, 1024);

  k_post<<<14336, 256, 0, stream>>>(past, gp, out_pk, out_pv, kr, vt, qr, tab);

  k_attn4<<<2048, 256, 0, stream>>>(qr, kr, vt, ctxb);

  dim3 g2(4096 / 128, 1024 / 128, 4);              // split-K=4: 1024 blocks
  k_gemm_bt<<<g2, 256, 0, stream>>>(ctxb, wo_bf, gp, 1024, 4096, 4096, 1024);
  k_reduce4<<<2048, 256, 0, stream>>>((const float4*)gp, (float4*)out_attn, 1048576, 1048576);
}

// Round 7
// 267.767 us; speedup vs baseline: 12.1239x; 1.5789x over previous
//
#include <hip/hip_runtime.h>
#include <cstdint>
#include <cstddef>

// ---------------- types / helpers ----------------
typedef __attribute__((ext_vector_type(4))) float f32x4;
typedef __attribute__((ext_vector_type(8))) unsigned short u16x8;
typedef __attribute__((ext_vector_type(4))) unsigned short u16x4;
typedef __bf16 bf16x8 __attribute__((ext_vector_type(8)));

__device__ __forceinline__ unsigned short f2bf(float f) {
  unsigned u = __builtin_bit_cast(unsigned, f);
  u += 0x7FFF + ((u >> 16) & 1);            // round-to-nearest-even
  return (unsigned short)(u >> 16);
}

__device__ __forceinline__ void mfma16x16x32(f32x4& acc, u16x8 a, u16x8 b) {
  acc = __builtin_amdgcn_mfma_f32_16x16x32_bf16(
      __builtin_bit_cast(bf16x8, a), __builtin_bit_cast(bf16x8, b), acc, 0, 0, 0);
}

typedef __attribute__((address_space(1))) const unsigned int as1_u32;
typedef __attribute__((address_space(3))) unsigned int as3_u32;
__device__ __forceinline__ void load_lds16(const void* g, void* l) {
  __builtin_amdgcn_global_load_lds((as1_u32*)g, (as3_u32*)l, 16, 0, 0);
}

// log2(e)/sqrt(128)
#define QSCALE2 0.12751745f

// ---------------- kernel 1: fused converts + rope table (1 launch) ----------------
// f4 ranges: hs [0,1048576) | w [1048576,10485760) | sincos tail [10485760,10616832)
__global__ void k_cvt_all(const float* __restrict__ hs, const float* __restrict__ wq,
                          const float* __restrict__ wk, const float* __restrict__ wv,
                          const float* __restrict__ wo,
                          unsigned short* __restrict__ hs_bf, unsigned short* __restrict__ w_bf,
                          float2* __restrict__ tab) {
  const int total = 10616832;
  int stride = gridDim.x * blockDim.x;
  for (int i = blockIdx.x * blockDim.x + threadIdx.x; i < total; i += stride) {
    if (i >= 10485760) {                    // sincos table, 2048x64
      int j = i - 10485760;
      int t = j >> 6, f = j & 63;
      float inv = expf(-(float)f * 0.14391156831212787f);  // 10000^(-f/64)
      float ang = (float)t * inv;
      tab[j] = make_float2(cosf(ang), sinf(ang));
      continue;
    }
    const float4* src;
    unsigned short* dst;
    long j;
    if (i < 1048576) { src = (const float4*)hs; j = i; dst = hs_bf + (size_t)i * 4; }
    else {
      int t = i - 1048576;
      dst = w_bf + (size_t)t * 4;           // q|k|v|o packed contiguously
      if (t < 4194304)      { src = (const float4*)wq; j = t; }
      else if (t < 4718592) { src = (const float4*)wk; j = t - 4194304; }
      else if (t < 5242880) { src = (const float4*)wv; j = t - 4718592; }
      else                  { src = (const float4*)wo; j = t - 5242880; }
    }
    float4 v = src[j];
    u16x4 o = { f2bf(v.x), f2bf(v.y), f2bf(v.z), f2bf(v.w) };
    *(u16x4*)dst = o;
  }
}

// ---------------- kernel 2: bf16 GEMM with split-K ----------------
__global__ __launch_bounds__(256) void k_gemm_bt(
    const unsigned short* __restrict__ A, const unsigned short* __restrict__ Bt,
    float* __restrict__ C, int M, int N, int K, int KC) {
  __shared__ unsigned short lA[2][128 * 32];
  __shared__ unsigned short lB[2][128 * 32];
  const int tid = threadIdx.x;
  const int w = tid >> 6, lane = tid & 63;
  const int wm = w >> 1, wn = w & 1;
  const int m0 = blockIdx.y * 128, n0 = blockIdx.x * 128;
  const int k0 = blockIdx.z * KC;
  const int lr = lane & 15, lg = lane >> 4;
  float* Cp = C + (size_t)blockIdx.z * M * N;

  f32x4 acc[4][4];
#pragma unroll
  for (int i = 0; i < 4; i++)
#pragma unroll
    for (int j = 0; j < 4; j++) acc[i][j] = (f32x4){0.f, 0.f, 0.f, 0.f};

  const int srow = w * 32 + (lane >> 2);
  const int scol = (lane & 3) * 8;
  const unsigned short* gA = A + (size_t)(m0 + srow) * K + scol;
  const unsigned short* gB = Bt + (size_t)(n0 + srow) * K + scol;

  auto stage = [&](int buf, int kt) {
#pragma unroll
    for (int c = 0; c < 2; c++) {
      load_lds16(gA + (size_t)c * 16 * K + kt, &lA[buf][(w * 32 + c * 16) * 32]);
      load_lds16(gB + (size_t)c * 16 * K + kt, &lB[buf][(w * 32 + c * 16) * 32]);
    }
  };

  stage(0, k0);
  __syncthreads();
  int cur = 0;
  for (int kt = k0; kt < k0 + KC; kt += 32) {
    if (kt + 32 < k0 + KC) stage(cur ^ 1, kt + 32);
    u16x8 af[4], bf[4];
#pragma unroll
    for (int i = 0; i < 4; i++) af[i] = *(const u16x8*)&lA[cur][(wm * 64 + i * 16 + lr) * 32 + lg * 8];
#pragma unroll
    for (int j = 0; j < 4; j++) bf[j] = *(const u16x8*)&lB[cur][(wn * 64 + j * 16 + lr) * 32 + lg * 8];
#pragma unroll
    for (int i = 0; i < 4; i++)
#pragma unroll
      for (int j = 0; j < 4; j++) mfma16x16x32(acc[i][j], af[i], bf[j]);
    __syncthreads();
    cur ^= 1;
  }
#pragma unroll
  for (int i = 0; i < 4; i++)
#pragma unroll
    for (int j = 0; j < 4; j++)
#pragma unroll
      for (int r = 0; r < 4; r++) {
        int row = m0 + wm * 64 + i * 16 + lg * 4 + r;
        int col = n0 + wn * 64 + j * 16 + lr;
        Cp[(size_t)row * N + col] = acc[i][j][r];
      }
}

// ---------------- kernel 3: split-K reduce (4 partials) — O-proj only ----------
__global__ void k_reduce4(const float4* __restrict__ p, float4* __restrict__ out,
                          int n4, size_t stride4) {
  int stridet = gridDim.x * blockDim.x;
  for (int i = blockIdx.x * blockDim.x + threadIdx.x; i < n4; i += stridet) {
    float4 a = p[i], b = p[i + stride4], c = p[i + 2 * stride4], d = p[i + 3 * stride4];
    out[i] = make_float4((a.x + b.x) + (c.x + d.x), (a.y + b.y) + (c.y + d.y),
                         (a.z + b.z) + (c.z + d.z), (a.w + b.w) + (c.w + d.w));
  }
}

// ---------------- kernel 4: fused post (reads GEMM1 partials directly) ----------
#define GP_S 5242880
__device__ __forceinline__ float gsum(const float* __restrict__ gp, size_t i) {
  return (gp[i] + gp[i + GP_S]) + (gp[i + 2 * (size_t)GP_S] + gp[i + 3 * (size_t)GP_S]);
}

__global__ void k_post(const float* __restrict__ past, const float* __restrict__ gp,
                       float* __restrict__ outk, float* __restrict__ outv,
                       unsigned short* __restrict__ kr, unsigned short* __restrict__ vt,
                       unsigned short* __restrict__ qr, const float2* __restrict__ tab) {
  int idx = blockIdx.x * blockDim.x + threadIdx.x;
  if (idx < 524288) {
    // K: new_past (pre-RoPE) + RoPE'd bf16 cache
    int d0 = idx & 63;
    int t = (idx >> 6) & 2047;
    int h = idx >> 17;
    float v1, v2;
    if (t < 1024) {
      const float* p = past + ((size_t)h * 1024 + t) * 128;
      v1 = p[d0]; v2 = p[d0 + 64];
    } else {
      size_t base = (size_t)(t - 1024) * 5120 + 4096 + h * 128;
      v1 = gsum(gp, base + d0); v2 = gsum(gp, base + d0 + 64);
    }
    float* o = outk + ((size_t)h * 2048 + t) * 128;
    o[d0] = v1; o[d0 + 64] = v2;
    float2 cs = tab[t * 64 + d0];
    unsigned short* ko = kr + ((size_t)h * 2048 + t) * 128;
    ko[d0]      = f2bf(v1 * cs.x - v2 * cs.y);
    ko[d0 + 64] = f2bf(v2 * cs.x + v1 * cs.y);
  } else if (idx < 1572864) {
    // V: new_past + transposed bf16 cache [4][128][2048]
    int i = idx - 524288;
    int d = i & 127;
    int t = (i >> 7) & 2047;
    int h = i >> 18;
    float val = (t < 1024) ? past[4 * 1024 * 128 + ((size_t)h * 1024 + t) * 128 + d]
                           : gsum(gp, (size_t)(t - 1024) * 5120 + 4608 + h * 128 + d);
    outv[((size_t)h * 2048 + t) * 128 + d] = val;
    vt[((size_t)h * 128 + d) * 2048 + t] = f2bf(val);
  } else {
    // Q: RoPE, pre-scaled by log2(e)/sqrt(D)
    int i = idx - 1572864;
    int d0 = i & 63;
    int q = (i >> 6) & 1023;
    int h = i >> 16;
    size_t base = (size_t)q * 5120 + h * 128;
    float v1 = gsum(gp, base + d0), v2 = gsum(gp, base + d0 + 64);
    float2 cs = tab[(1024 + q) * 64 + d0];
    unsigned short* o = qr + ((size_t)h * 1024 + q) * 128;
    o[d0]      = f2bf((v1 * cs.x - v2 * cs.y) * QSCALE2);
    o[d0 + 64] = f2bf((v2 * cs.x + v1 * cs.y) * QSCALE2);
  }
}

// ---------------- kernel 5: flash attention, 8-wave shared-KV LDS staging ------
// grid 256 = 32 heads x 8 q-chunks (128 rows). Wave w owns q-rows
// q0 = c*128+w*16. K tile [64 keys][128 d] and V^T tile [128 d][64 keys] staged
// via global_load_lds, double-buffered, XOR-swizzled (byte ^= (row&7)<<4) with
// pre-swizzled global source (rule #21: same involution on stage and read).
// One __syncthreads per 64-key tile; stage(t+1) issued before compute(t).
__global__ __launch_bounds__(512) void k_attn8(
    const unsigned short* __restrict__ qr,  // [32][1024][128] (pre-scaled, log2)
    const unsigned short* __restrict__ kr,  // [4][2048][128] (RoPE'd)
    const unsigned short* __restrict__ vt,  // [4][128][2048]
    unsigned short* __restrict__ ctxb) {    // [1024][4096] bf16
  __shared__ unsigned short k_lds[2][64 * 128];   // 32 KB, [key][d] swizzled
  __shared__ unsigned short v_lds[2][128 * 64];   // 32 KB, [d][key] swizzled
  __shared__ unsigned short plds[8][640];         // 10 KB, per-wave P tile (80B rows)
  const int bid = blockIdx.x;
  const int h = bid >> 3;
  const int c = bid & 7;
  const int kvh = h >> 3;
  const int tid = threadIdx.x;
  const int w = tid >> 6, l = tid & 63;
  const int lr = l & 15, lg = l >> 4;
  const int q0 = c * 128 + w * 16;
  const unsigned short* kh = kr + (size_t)kvh * 2048 * 128;
  const unsigned short* vh = vt + (size_t)kvh * 128 * 2048;

  u16x8 qf[4];
  {
    const unsigned short* qb = qr + ((size_t)(h * 1024 + q0 + lr)) * 128 + lg * 8;
#pragma unroll
    for (int ks = 0; ks < 4; ks++) qf[ks] = *(const u16x8*)(qb + ks * 32);
  }
  f32x4 acc[8];
#pragma unroll
  for (int i = 0; i < 8; i++) acc[i] = (f32x4){0.f, 0.f, 0.f, 0.f};
  float m_r = -1e30f, l_r = 0.f;

  const int limit = 1024 + q0 + lr;         // this lane's query position
  const int mylimit = 1024 + q0 + 15;       // wave's last needed key
  const int T = 18 + 2 * c;                 // 64-key tiles (covers 1152+128c keys)

  // stage K tile [64][128]: 16 KB = 2 issues x 512 thr x 16B. LDS linear;
  // source colbyte pre-XOR'd so LDS[row][cb] = global[row][cb ^ (row&7)<<4].
  auto stageK = [&](int buf, int kb) {
#pragma unroll
    for (int i = 0; i < 2; i++) {
      int loff = i * 8192 + tid * 16;
      int row = loff >> 8;
      int scb = (loff & 255) ^ ((row & 7) << 4);
      load_lds16((const char*)(kh + (size_t)(kb + row) * 128) + scb,
                 (char*)&k_lds[buf][0] + loff);
    }
  };
  // stage V^T tile [128][64]: rows are 128B windows of vt's 2048-key rows.
  auto stageV = [&](int buf, int kb) {
#pragma unroll
    for (int i = 0; i < 2; i++) {
      int loff = i * 8192 + tid * 16;
      int row = loff >> 7;
      int scb = (loff & 127) ^ ((row & 7) << 4);
      load_lds16((const char*)(vh + (size_t)row * 2048 + kb) + scb,
                 (char*)&v_lds[buf][0] + loff);
    }
  };

  stageK(0, 0); stageV(0, 0);
  __syncthreads();
  int cur = 0;
  for (int t = 0; t < T; t++) {
    if (t + 1 < T) { stageK(cur ^ 1, (t + 1) * 64); stageV(cur ^ 1, (t + 1) * 64); }
    if (t * 64 <= mylimit) {                // wave-uniform skip of dead tail tiles
#pragma unroll
      for (int kc = 0; kc < 2; kc++) {
        const int kb = t * 64 + kc * 32;    // global key base of this 32-chunk
        if (kb > mylimit) continue;         // wave-uniform
        f32x4 s[2];
#pragma unroll
        for (int sub = 0; sub < 2; sub++) {
          f32x4 a = (f32x4){0.f, 0.f, 0.f, 0.f};
          const int key = kc * 32 + sub * 16 + lr;   // local key 0..63
          const int swz = (key & 7) << 4;
#pragma unroll
          for (int ks = 0; ks < 4; ks++) {
            int addr = key * 256 + ((ks * 64 + lg * 16) ^ swz);
            u16x8 kf = *(const u16x8*)((const char*)&k_lds[cur][0] + addr);
            mfma16x16x32(a, kf, qf[ks]);    // A=K, B=Q -> S^T
          }
          s[sub] = a;
        }
        float v[8];
#pragma unroll
        for (int r = 0; r < 4; r++) { v[r] = s[0][r]; v[4 + r] = s[1][r]; }
        if (kb + 31 > 1024 + q0) {          // diagonal chunks only: causal mask
          const int kbase = kb + lg * 4;
#pragma unroll
          for (int r = 0; r < 4; r++) {
            if (kbase + r > limit)      v[r]     = -1e30f;
            if (kbase + 16 + r > limit) v[4 + r] = -1e30f;
          }
        }
        float tmax = v[0];
#pragma unroll
        for (int j = 1; j < 8; j++) tmax = fmaxf(tmax, v[j]);
        tmax = fmaxf(tmax, __shfl_xor(tmax, 16));
        tmax = fmaxf(tmax, __shfl_xor(tmax, 32));
        if (!__all(tmax <= m_r + 11.5f)) {  // defer-max (T13)
          float mn = fmaxf(m_r, tmax);
          float corr = exp2f(m_r - mn);
          m_r = mn;
          l_r *= corr;
#pragma unroll
          for (int nt = 0; nt < 8; nt++)
#pragma unroll
            for (int r = 0; r < 4; r++) acc[nt][r] *= corr;
        }
        float p[8];
        float psum = 0.f;
#pragma unroll
        for (int j = 0; j < 8; j++) { p[j] = exp2f(v[j] - m_r); psum += p[j]; }
        psum += __shfl_xor(psum, 16);
        psum += __shfl_xor(psum, 32);
        l_r += psum;
        unsigned wds[4];
#pragma unroll
        for (int j = 0; j < 4; j++) {
          unsigned lo = __builtin_bit_cast(unsigned, p[2 * j]) + 0x8000u;
          unsigned hi = __builtin_bit_cast(unsigned, p[2 * j + 1]) + 0x8000u;
          wds[j] = (hi & 0xFFFF0000u) | (lo >> 16);
        }
        char* pb = (char*)&plds[w][0] + lr * 80 + lg * 8;
        *(uint2*)(pb)      = make_uint2(wds[0], wds[1]);
        *(uint2*)(pb + 32) = make_uint2(wds[2], wds[3]);
        asm volatile("s_waitcnt lgkmcnt(0)" ::: "memory");  // P write->read, 1 wave
        u16x8 pf = *(const u16x8*)&plds[w][lr * 40 + lg * 8];
#pragma unroll
        for (int nt = 0; nt < 8; nt++) {
          const int d = nt * 16 + lr;
          int addr = d * 128 + ((kc * 64 + lg * 16) ^ ((d & 7) << 4));
          u16x8 vf = *(const u16x8*)((const char*)&v_lds[cur][0] + addr);
          mfma16x16x32(acc[nt], vf, pf);    // A=V^T, B=P -> ctx^T
        }
      }
    }
    __syncthreads();                        // drains stage(t+1); protects cur^1
    cur ^= 1;
  }
  // epilogue: per-wave direct store; acc[nt][r] = ctx[q0+lr][nt*16+lg*4+r]
  float inv = 1.0f / l_r;
  unsigned short* ob = ctxb + (size_t)(q0 + lr) * 4096 + h * 128 + lg * 4;
#pragma unroll
  for (int nt = 0; nt < 8; nt++) {
    u16x4 o = { f2bf(acc[nt][0] * inv), f2bf(acc[nt][1] * inv),
                f2bf(acc[nt][2] * inv), f2bf(acc[nt][3] * inv) };
    *(u16x4*)(ob + nt * 16) = o;
  }
}

// ---------------- launch ----------------
extern "C" void kernel_launch(void* const* d_in, const int* in_sizes, int n_in,
                              void* d_out, int out_size, void* d_ws, size_t ws_size,
                              hipStream_t stream) {
  (void)in_sizes; (void)n_in; (void)out_size; (void)ws_size;
  const float* hs   = (const float*)d_in[0];
  const float* past = (const float*)d_in[1];
  // d_in[2] attention_mask: pure causal, synthesized analytically
  const float* Wq = (const float*)d_in[3];
  const float* Wk = (const float*)d_in[4];
  const float* Wv = (const float*)d_in[5];
  const float* Wo = (const float*)d_in[6];

  float* out_attn = (float*)d_out;                 // [1024][4096]
  float* out_pk = out_attn + 4194304;              // [4][2048][128]
  float* out_pv = out_pk + 1048576;                // [4][2048][128]

  const size_t MB = 1048576;
  char* ws = (char*)d_ws;
  unsigned short* hs_bf   = (unsigned short*)(ws);              // 8 MB
  unsigned short* wqkv_bf = (unsigned short*)(ws + 8 * MB);     // 40 MB [5120][4096]
  unsigned short* wo_bf   = (unsigned short*)(ws + 48 * MB);    // 32 MB [4096][4096]
  float2*         tab     = (float2*)(ws + 100 * MB);           // 1 MB
  unsigned short* kr      = (unsigned short*)(ws + 101 * MB);   // 2 MB
  unsigned short* vt      = (unsigned short*)(ws + 103 * MB);   // 2 MB
  unsigned short* qr      = (unsigned short*)(ws + 105 * MB);   // 8 MB
  unsigned short* ctxb    = (unsigned short*)(ws + 113 * MB);   // 8 MB
  float*          gp      = (float*)(ws + 128 * MB);            // 80 MB GEMM partials

  k_cvt_all<<<2048, 256, 0, stream>>>(hs, Wq, Wk, Wv, Wo, hs_bf, wqkv_bf, tab);

  dim3 g1(5120 / 128, 1024 / 128, 4);              // split-K=4: 1280 blocks
  k_gemm_bt<<<g1, 256, 0, stream>>>(hs_bf, wqkv_bf, gp, 1024, 5120, 4096, 1024);

  k_post<<<14336, 256, 0, stream>>>(past, gp, out_pk, out_pv, kr, vt, qr, tab);

  k_attn8<<<256, 512, 0, stream>>>(qr, kr, vt, ctxb);

  dim3 g2(4096 / 128, 1024 / 128, 4);              // split-K=4: 1024 blocks
  k_gemm_bt<<<g2, 256, 0, stream>>>(ctxb, wo_bf, gp, 1024, 4096, 4096, 1024);
  k_reduce4<<<2048, 256, 0, stream>>>((const float4*)gp, (float4*)out_attn, 1048576, 1048576);
}